// Round 1
// baseline (1121.330 us; speedup 1.0000x reference)
//
#include <hip/hip_runtime.h>

#define N_ROWS 262144
#define DIM 64
#define KCODES 512
#define THREADS 512
#define BLK_ROWS 128                       // 8 waves x 16 rows
#define NBLOCKS (N_ROWS / BLK_ROWS)        // 2048
#define CHUNK 128                          // codes staged in LDS per pass
#define NCHUNK (KCODES / CHUNK)            // 4
#define MARGIN_T 1.0e-4f                   // covers 512-ulp key quant + 3-pass bf16 err + np-fp32 dot noise

// d_out is FLOAT32. Flat layout in return order:
// [0] loss | [1 .. 1+N*D) quantized | [1+N*D] norm_perplexity | [2+N*D ..) indices
#define OFF_Q 1
#define OFF_PERP (1 + (size_t)N_ROWS * DIM)
#define OFF_IDX (2 + (size_t)N_ROWS * DIM)

typedef __attribute__((ext_vector_type(8))) short bf16x8;
typedef __attribute__((ext_vector_type(4))) float f32x4;

// ---------- numerics helpers (numpy-exact machinery, carried over) ----------

// numpy pairwise sum of squares for n=64 (loops.c.src): 8 strided accumulators,
// sequential adds, fixed combine tree. contract(off): square rounds BEFORE add.
__device__ __forceinline__ float np_sum_sq64(const float* __restrict__ v) {
#pragma clang fp contract(off)
    float r[8];
#pragma unroll
    for (int l = 0; l < 8; ++l) r[l] = v[l] * v[l];
#pragma unroll
    for (int k = 1; k < 8; ++k) {
#pragma unroll
        for (int l = 0; l < 8; ++l) {
            float sq = v[8 * k + l] * v[8 * k + l];
            r[l] = r[l] + sq;
        }
    }
    return ((r[0] + r[1]) + (r[2] + r[3])) + ((r[4] + r[5]) + (r[6] + r[7]));
}

// Exact replication of numpy's fp32 distance for one (row, code):
// e = fp32( fp32(A + B_j) - fp32(2*dot) ), dot accurate via fp64.
__device__ __forceinline__ float np_e(const float* __restrict__ W, int idx,
                                      const float* __restrict__ x, float A, float Bj) {
#pragma clang fp contract(off)
    const float* w = W + (size_t)idx * DIM;
    double dot = 0.0;
#pragma unroll
    for (int d = 0; d < DIM; ++d) dot = fma((double)w[d], (double)x[d], dot);
    float C2 = (float)(2.0 * dot);
    float AB = A + Bj;
    return AB - C2;
}

// fp32 -> bf16 bits, round-to-nearest-even
__device__ __forceinline__ unsigned short f2bf(float f) {
    unsigned u = __float_as_uint(f);
    u += 0x7FFFu + ((u >> 16) & 1u);
    return (unsigned short)(u >> 16);
}
__device__ __forceinline__ float bf2f(unsigned short h) {
    return __uint_as_float((unsigned)h << 16);
}

// sortable-key <-> float. key = transform(t) with low 9 bits replaced by code idx.
__device__ __forceinline__ unsigned t2key(float t, unsigned idx) {
    int iu = __float_as_int(t);
    unsigned u = ((unsigned)iu) ^ (((unsigned)(iu >> 31)) | 0x80000000u);
    return (u & 0xFFFFFE00u) | idx;
}
__device__ __forceinline__ float key2t(unsigned key) {
    unsigned u = key & 0xFFFFFE00u;
    unsigned f = (u & 0x80000000u) ? (u & 0x7FFFFFFFu) : ~u;
    return __uint_as_float(f);
}

// ---------- prep: W_hi/W_lo (bf16 of -2W, split) + numpy ||w||^2 ----------

__global__ __launch_bounds__(256) void vq_prep(const float* __restrict__ W,
        unsigned short* __restrict__ WhiG, unsigned short* __restrict__ WloG,
        float* __restrict__ Bsc) {
    int c = blockIdx.x * 256 + threadIdx.x;
    if (c >= KCODES) return;
    const float* w = W + (size_t)c * DIM;
    Bsc[c] = np_sum_sq64(w);                 // numpy summation order
#pragma unroll 4
    for (int d = 0; d < DIM; ++d) {
        float v = -2.0f * w[d];              // exact scale
        unsigned short hi = f2bf(v);
        unsigned short lo = f2bf(v - bf2f(hi));   // split residual, exact subtract
        WhiG[c * DIM + d] = hi;
        WloG[c * DIM + d] = lo;
    }
}

// ---------- main: MFMA distance + packed-key min1/min2 argmin ----------
// Wave w owns rows [16w,16w+16). MFMA 16x16x32_bf16: A = -2W (M=codes),
// B = X (N=rows), C-init = B_j. 3 passes: ah*xh + ah*xl + al*xh.
// D layout (m89-verified): col=lane&15 (row n), row=(lane>>4)*4+reg (code m).

__global__ __launch_bounds__(THREADS, 4) void vq_argmin(
    const float* __restrict__ X,
    const unsigned short* __restrict__ WhiG,
    const unsigned short* __restrict__ WloG,
    const float* __restrict__ Bsc,
    float* __restrict__ out) {

    __shared__ __align__(16) unsigned short sHi[CHUNK * DIM];  // 16 KiB, swizzled
    __shared__ __align__(16) unsigned short sLo[CHUNK * DIM];  // 16 KiB, swizzled
    __shared__ __align__(16) float sX[BLK_ROWS * DIM];         // 32 KiB, swizzled
    __shared__ __align__(16) float sB[KCODES];                 // 2 KiB

    const int tid = threadIdx.x;
    const int w = tid >> 6;          // wave 0..7
    const int l = tid & 63;          // lane
    const int q = l >> 4;            // lane quad 0..3
    const int r16 = l & 15;          // n / m sub-index
    const int R0 = blockIdx.x * BLK_ROWS;

    // ---- stage X tile (coalesced load, XOR-swizzled store: byte ^= (r&7)<<5) ----
    {
        const float4* g = (const float4*)(X + (size_t)R0 * DIM);
        char* base = (char*)sX;
#pragma unroll
        for (int i = 0; i < (BLK_ROWS * DIM / 4) / THREADS; ++i) {   // 4
            int fidx = tid + THREADS * i;                            // [0,2048)
            int r = fidx >> 4, c4 = fidx & 15;
            int off = (r * 256 + c4 * 16) ^ ((r & 7) << 5);
            *(float4*)(base + off) = g[fidx];
        }
        sB[tid] = Bsc[tid];   // THREADS == KCODES
    }
    __syncthreads();

    // ---- per-lane X fragments: row r = 16w + (l&15), k = 32h + 8q + j ----
    bf16x8 xh[2], xl[2];
    {
        const int r = w * 16 + r16;
        const char* base = (const char*)sX;
#pragma unroll
        for (int h = 0; h < 2; ++h) {
            int b0 = (r * 256 + h * 128 + q * 32) ^ ((r & 7) << 5);
            float4 fa = *(const float4*)(base + b0);
            float4 fb = *(const float4*)(base + b0 + 16);   // bit4 untouched by swizzle
            float f[8] = {fa.x, fa.y, fa.z, fa.w, fb.x, fb.y, fb.z, fb.w};
            bf16x8 hi8, lo8;
#pragma unroll
            for (int j = 0; j < 8; ++j) {
                unsigned short hi = f2bf(f[j]);
                unsigned short lo = f2bf(f[j] - bf2f(hi));
                hi8[j] = (short)hi; lo8[j] = (short)lo;
            }
            xh[h] = hi8; xl[h] = lo8;
        }
    }

    unsigned min1 = 0xFFFFFFFFu, min2 = 0xFFFFFFFFu;

    for (int cc = 0; cc < NCHUNK; ++cc) {
        const int c0 = cc * CHUNK;
        __syncthreads();
        {   // stage -2W chunk hi+lo (coalesced uint4, swizzle: byte ^= (c&7)<<4)
            const uint4* gh = (const uint4*)(WhiG + (size_t)c0 * DIM);
            const uint4* gl = (const uint4*)(WloG + (size_t)c0 * DIM);
            char* bh = (char*)sHi; char* bl = (char*)sLo;
#pragma unroll
            for (int i = 0; i < (CHUNK * DIM / 8) / THREADS; ++i) {  // 2
                int idx = tid + THREADS * i;                          // uint4 idx
                int c = idx >> 3, k8 = idx & 7;
                int off = (c * 128 + k8 * 16) ^ ((c & 7) << 4);
                *(uint4*)(bh + off) = gh[idx];
                *(uint4*)(bl + off) = gl[idx];
            }
        }
        __syncthreads();

#pragma unroll
        for (int ct = 0; ct < CHUNK / 16; ++ct) {
            const int cloc = ct * 16 + r16;     // chunk-local code row of A frag
            const char* bh = (const char*)sHi;
            const char* bl = (const char*)sLo;
            const int sw = (cloc & 7) << 4;
            int o0 = (cloc * 128 + 16 * q) ^ sw;          // k-half 0
            int o1 = (cloc * 128 + 64 + 16 * q) ^ sw;     // k-half 1
            bf16x8 ah0 = *(const bf16x8*)(bh + o0);
            bf16x8 ah1 = *(const bf16x8*)(bh + o1);
            bf16x8 al0 = *(const bf16x8*)(bl + o0);
            bf16x8 al1 = *(const bf16x8*)(bl + o1);

            // C-init = B_j for this lane's 4 codes -> acc ends as t = B - 2*dot
            f32x4 acc = *(const f32x4*)&sB[c0 + ct * 16 + q * 4];

            acc = __builtin_amdgcn_mfma_f32_16x16x32_bf16(ah0, xh[0], acc, 0, 0, 0);
            acc = __builtin_amdgcn_mfma_f32_16x16x32_bf16(ah1, xh[1], acc, 0, 0, 0);
            acc = __builtin_amdgcn_mfma_f32_16x16x32_bf16(ah0, xl[0], acc, 0, 0, 0);
            acc = __builtin_amdgcn_mfma_f32_16x16x32_bf16(ah1, xl[1], acc, 0, 0, 0);
            acc = __builtin_amdgcn_mfma_f32_16x16x32_bf16(al0, xh[0], acc, 0, 0, 0);
            acc = __builtin_amdgcn_mfma_f32_16x16x32_bf16(al1, xh[1], acc, 0, 0, 0);

            const unsigned jbase = (unsigned)(c0 + ct * 16 + q * 4);
#pragma unroll
            for (int r = 0; r < 4; ++r) {
                unsigned key = t2key(acc[r], jbase + (unsigned)r);
                unsigned mx = min1 > key ? min1 : key;
                min2 = min2 < mx ? min2 : mx;
                min1 = min1 < key ? min1 : key;
            }
        }
    }

    // ---- merge the 4 lane-subsets of each row (lanes l, l^16, l^32, l^48) ----
#pragma unroll
    for (int d = 16; d <= 32; d <<= 1) {
        unsigned o1 = (unsigned)__shfl_xor((int)min1, d, 64);
        unsigned o2 = (unsigned)__shfl_xor((int)min2, d, 64);
        unsigned n1 = min1 < o1 ? min1 : o1;
        unsigned mx = min1 > o1 ? min1 : o1;
        unsigned mn = min2 < o2 ? min2 : o2;
        unsigned n2 = mx < mn ? mx : mn;
        min1 = n1; min2 = n2;
    }

    if (q == 0) {   // row owner: lanes 0..15 -> 16 consecutive rows, coalesced
        const int row = R0 + w * 16 + r16;
        unsigned best = min1 & 511u;
        float t1 = key2t(min1), t2 = key2t(min2);
        // flag rows whose runner-up is within margin: fixup re-resolves exactly
        float v = (float)best + ((t2 < t1 + MARGIN_T) ? 1024.0f : 0.0f);
        out[OFF_IDX + row] = v;
    }
}

// ---------- fixup: exact numpy-fp32 argmin over ALL 512 codes, flagged rows ----------

__global__ __launch_bounds__(256) void vq_fixup(
    const float* __restrict__ X, const float* __restrict__ W,
    const float* __restrict__ Bsc, float* __restrict__ out) {
    __shared__ float sx[DIM];
    __shared__ unsigned long long sKey[256];
    __shared__ float sFlagged[64];
    const int t = threadIdx.x;
    const int r0 = blockIdx.x * 64;

    if (t < 64) sFlagged[t] = out[OFF_IDX + r0 + t];
    __syncthreads();

    for (int i = 0; i < 64; ++i) {
        if (sFlagged[i] < 1024.0f) continue;    // uniform across block
        const int row = r0 + i;
        if (t < 64) sx[t] = X[(size_t)row * DIM + t];
        __syncthreads();
        const float A = np_sum_sq64(sx);        // numpy order, identical bits everywhere
        unsigned long long bk = ~0ULL;
        for (int c = t; c < KCODES; c += 256) {
            float e = np_e(W, c, sx, A, Bsc[c]);
            int iu = __float_as_int(e);
            unsigned u = ((unsigned)iu) ^ (((unsigned)(iu >> 31)) | 0x80000000u);
            unsigned long long key = ((unsigned long long)u << 32) | (unsigned)c;
            bk = bk < key ? bk : key;           // exact e, first-index tie-break
        }
        sKey[t] = bk;
        __syncthreads();
        for (int s = 128; s; s >>= 1) {
            if (t < s) { unsigned long long o = sKey[t + s]; if (o < sKey[t]) sKey[t] = o; }
            __syncthreads();
        }
        if (t == 0) out[OFF_IDX + row] = (float)(unsigned)(sKey[0] & 511ULL);
        __syncthreads();
    }
}

// ---------- scatter: gather W[best] -> Q, elementwise SSE, histogram ----------
// One wave per row. Runs on FINAL indices (post-fixup).

__global__ __launch_bounds__(256) void vq_scatter(
    const float* __restrict__ X, const float* __restrict__ W,
    float* __restrict__ out, double* __restrict__ sseAcc,
    unsigned* __restrict__ gHist) {
    __shared__ float sP[4];
    const int tid = threadIdx.x;
    const int row = blockIdx.x * 4 + (tid >> 6);
    const int lane = tid & 63;
    int idx = (int)out[OFF_IDX + row];
    if ((unsigned)idx >= KCODES) idx = KCODES - 1;   // safety clamp
    const float wv = W[(size_t)idx * DIM + lane];
    const float xv = X[(size_t)row * DIM + lane];
    out[OFF_Q + (size_t)row * DIM + lane] = wv;
    float d = wv - xv;
    float p = d * d;
#pragma unroll
    for (int off = 32; off; off >>= 1) p += __shfl_down(p, off);
    if (lane == 0) {
        atomicAdd(&gHist[idx], 1u);
        sP[tid >> 6] = p;
    }
    __syncthreads();
    if (tid == 0) {
        double s = (double)sP[0] + (double)sP[1] + (double)sP[2] + (double)sP[3];
        atomicAdd(sseAcc, s);                    // fp64 accumulate: bias-free loss
    }
}

// ---------- finalize ----------

__global__ __launch_bounds__(512) void vq_finalize(
    const double* __restrict__ sseAcc, const unsigned* __restrict__ gHist,
    float* __restrict__ out) {
    __shared__ float partial[8];
    const int t = threadIdx.x;
    float p = (float)gHist[t] * (1.0f / (float)N_ROWS);
    float v = p * logf(p + 1e-10f);
#pragma unroll
    for (int off = 32; off; off >>= 1) v += __shfl_down(v, off);
    if ((t & 63) == 0) partial[t >> 6] = v;
    __syncthreads();
    if (t == 0) {
        float s = 0.f;
#pragma unroll
        for (int i = 0; i < 8; ++i) s += partial[i];
        out[OFF_PERP] = expf(-s) * (1.0f / (float)KCODES);
        out[0] = (float)(1.25 * sseAcc[0] * (1.0 / ((double)N_ROWS * (double)DIM)));
    }
}

extern "C" void kernel_launch(void* const* d_in, const int* in_sizes, int n_in,
                              void* d_out, int out_size, void* d_ws, size_t ws_size,
                              hipStream_t stream) {
    const float* X = (const float*)d_in[0];
    const float* W = (const float*)d_in[1];
    float* out = (float*)d_out;
    double* sseAcc = (double*)d_ws;
    unsigned* gHist = (unsigned*)((char*)d_ws + 64);

    size_t zb = 64 + KCODES * sizeof(unsigned);      // 2112 B of ws used
    if (zb > ws_size) zb = ws_size;
    hipMemsetAsync(d_ws, 0, zb, stream);

    // Scratch for prep outputs lives in the quantized region of `out`
    // (dead until vq_scatter overwrites it; consumed by vq_argmin/vq_fixup).
    float* scratch = out + OFF_Q;
    unsigned short* WhiG = (unsigned short*)scratch;              // 64 KiB
    unsigned short* WloG = WhiG + (size_t)KCODES * DIM;           // 64 KiB
    float* Bsc = (float*)(WloG + (size_t)KCODES * DIM);           // 2 KiB

    vq_prep<<<2, 256, 0, stream>>>(W, WhiG, WloG, Bsc);
    vq_argmin<<<NBLOCKS, THREADS, 0, stream>>>(X, WhiG, WloG, Bsc, out);
    vq_fixup<<<N_ROWS / 64, 256, 0, stream>>>(X, W, Bsc, out);
    vq_scatter<<<N_ROWS / 4, 256, 0, stream>>>(X, W, out, sseAcc, gHist);
    vq_finalize<<<1, 512, 0, stream>>>(sseAcc, gHist, out);
}

// Round 2
// 339.961 us; speedup vs baseline: 3.2984x; 3.2984x over previous
//
#include <hip/hip_runtime.h>

#define N_ROWS 262144
#define DIM 64
#define KCODES 512
#define THREADS 512
#define BLK_ROWS 128                       // 8 waves x 16 rows
#define NBLOCKS (N_ROWS / BLK_ROWS)        // 2048
#define CHUNK 128                          // codes staged in LDS per pass
#define NCHUNK (KCODES / CHUNK)            // 4
#define NPART 64                           // partial histograms (contention spread)
#define MARGIN_T 1.0e-4f                   // covers 512-ulp key quant + 3-pass bf16 err + np-fp32 dot noise

// d_out is FLOAT32. Flat layout in return order:
// [0] loss | [1 .. 1+N*D) quantized | [1+N*D] norm_perplexity | [2+N*D ..) indices
#define OFF_Q 1
#define OFF_PERP (1 + (size_t)N_ROWS * DIM)
#define OFF_IDX (2 + (size_t)N_ROWS * DIM)

typedef __attribute__((ext_vector_type(8))) short bf16x8;
typedef __attribute__((ext_vector_type(4))) float f32x4;

// ---------- numerics helpers (numpy-exact machinery, carried over) ----------

// numpy pairwise sum of squares for n=64 (loops.c.src): 8 strided accumulators,
// sequential adds, fixed combine tree. contract(off): square rounds BEFORE add.
__device__ __forceinline__ float np_sum_sq64(const float* __restrict__ v) {
#pragma clang fp contract(off)
    float r[8];
#pragma unroll
    for (int l = 0; l < 8; ++l) r[l] = v[l] * v[l];
#pragma unroll
    for (int k = 1; k < 8; ++k) {
#pragma unroll
        for (int l = 0; l < 8; ++l) {
            float sq = v[8 * k + l] * v[8 * k + l];
            r[l] = r[l] + sq;
        }
    }
    return ((r[0] + r[1]) + (r[2] + r[3])) + ((r[4] + r[5]) + (r[6] + r[7]));
}

// Exact replication of numpy's fp32 distance for one (row, code):
// e = fp32( fp32(A + B_j) - fp32(2*dot) ), dot accurate via fp64.
__device__ __forceinline__ float np_e(const float* __restrict__ W, int idx,
                                      const float* __restrict__ x, float A, float Bj) {
#pragma clang fp contract(off)
    const float* w = W + (size_t)idx * DIM;
    double dot = 0.0;
#pragma unroll
    for (int d = 0; d < DIM; ++d) dot = fma((double)w[d], (double)x[d], dot);
    float C2 = (float)(2.0 * dot);
    float AB = A + Bj;
    return AB - C2;
}

// fp32 -> bf16 bits, round-to-nearest-even
__device__ __forceinline__ unsigned short f2bf(float f) {
    unsigned u = __float_as_uint(f);
    u += 0x7FFFu + ((u >> 16) & 1u);
    return (unsigned short)(u >> 16);
}
__device__ __forceinline__ float bf2f(unsigned short h) {
    return __uint_as_float((unsigned)h << 16);
}

// sortable-key <-> float. key = transform(t) with low 9 bits replaced by code idx.
__device__ __forceinline__ unsigned t2key(float t, unsigned idx) {
    int iu = __float_as_int(t);
    unsigned u = ((unsigned)iu) ^ (((unsigned)(iu >> 31)) | 0x80000000u);
    return (u & 0xFFFFFE00u) | idx;
}
__device__ __forceinline__ float key2t(unsigned key) {
    unsigned u = key & 0xFFFFFE00u;
    unsigned f = (u & 0x80000000u) ? (u & 0x7FFFFFFFu) : ~u;
    return __uint_as_float(f);
}

// ---------- prep: W_hi/W_lo (bf16 of -2W, split) + numpy ||w||^2 ----------

__global__ __launch_bounds__(256) void vq_prep(const float* __restrict__ W,
        unsigned short* __restrict__ WhiG, unsigned short* __restrict__ WloG,
        float* __restrict__ Bsc) {
    int c = blockIdx.x * 256 + threadIdx.x;
    if (c >= KCODES) return;
    const float* w = W + (size_t)c * DIM;
    Bsc[c] = np_sum_sq64(w);                 // numpy summation order
#pragma unroll 4
    for (int d = 0; d < DIM; ++d) {
        float v = -2.0f * w[d];              // exact scale
        unsigned short hi = f2bf(v);
        unsigned short lo = f2bf(v - bf2f(hi));   // split residual, exact subtract
        WhiG[c * DIM + d] = hi;
        WloG[c * DIM + d] = lo;
    }
}

// ---------- main: MFMA distance + packed-key min1/min2 argmin + SSE + hist ----------
// Wave w owns rows [16w,16w+16). MFMA 16x16x32_bf16: A = -2W (M=codes),
// B = X (N=rows), C-init = B_j. 3 passes: ah*xh + ah*xl + al*xh.
// D layout (m89-verified): col=lane&15 (row n), row=(lane>>4)*4+reg (code m).
// SSE_row = ||x||^2 + t1 (unflagged rows only; flagged rows handled by fixup).

__global__ __launch_bounds__(THREADS, 4) void vq_argmin(
    const float* __restrict__ X,
    const unsigned short* __restrict__ WhiG,
    const unsigned short* __restrict__ WloG,
    const float* __restrict__ Bsc,
    float* __restrict__ out,
    double* __restrict__ sseAcc,
    unsigned* __restrict__ gHistP) {

    __shared__ __align__(16) unsigned short sHi[CHUNK * DIM];  // 16 KiB, swizzled
    __shared__ __align__(16) unsigned short sLo[CHUNK * DIM];  // 16 KiB, swizzled
    __shared__ __align__(16) float sX[BLK_ROWS * DIM];         // 32 KiB, swizzled
    __shared__ __align__(16) float sB[KCODES];                 // 2 KiB
    __shared__ unsigned sHist[KCODES];                         // 2 KiB
    __shared__ double sSseW[8];

    const int tid = threadIdx.x;
    const int w = tid >> 6;          // wave 0..7
    const int l = tid & 63;          // lane
    const int q = l >> 4;            // lane quad 0..3
    const int r16 = l & 15;          // n / m sub-index
    const int R0 = blockIdx.x * BLK_ROWS;

    // ---- stage X tile (coalesced load, XOR-swizzled store: byte ^= (r&7)<<5) ----
    {
        const float4* g = (const float4*)(X + (size_t)R0 * DIM);
        char* base = (char*)sX;
#pragma unroll
        for (int i = 0; i < (BLK_ROWS * DIM / 4) / THREADS; ++i) {   // 4
            int fidx = tid + THREADS * i;                            // [0,2048)
            int r = fidx >> 4, c4 = fidx & 15;
            int off = (r * 256 + c4 * 16) ^ ((r & 7) << 5);
            *(float4*)(base + off) = g[fidx];
        }
        sB[tid] = Bsc[tid];   // THREADS == KCODES
        sHist[tid] = 0u;
    }
    __syncthreads();

    // ---- per-lane X fragments: row r = 16w + (l&15), k = 32h + 8q + j ----
    // asum = lane's partial ||x||^2 over its 16 covered dims.
    bf16x8 xh[2], xl[2];
    float asum = 0.f;
    {
        const int r = w * 16 + r16;
        const char* base = (const char*)sX;
#pragma unroll
        for (int h = 0; h < 2; ++h) {
            int b0 = (r * 256 + h * 128 + q * 32) ^ ((r & 7) << 5);
            float4 fa = *(const float4*)(base + b0);
            float4 fb = *(const float4*)(base + b0 + 16);   // bit4 untouched by swizzle
            float f[8] = {fa.x, fa.y, fa.z, fa.w, fb.x, fb.y, fb.z, fb.w};
            bf16x8 hi8, lo8;
#pragma unroll
            for (int j = 0; j < 8; ++j) {
                asum = fmaf(f[j], f[j], asum);
                unsigned short hi = f2bf(f[j]);
                unsigned short lo = f2bf(f[j] - bf2f(hi));
                hi8[j] = (short)hi; lo8[j] = (short)lo;
            }
            xh[h] = hi8; xl[h] = lo8;
        }
    }

    unsigned min1 = 0xFFFFFFFFu, min2 = 0xFFFFFFFFu;

    for (int cc = 0; cc < NCHUNK; ++cc) {
        const int c0 = cc * CHUNK;
        __syncthreads();
        {   // stage -2W chunk hi+lo (coalesced uint4, swizzle: byte ^= (c&7)<<4)
            const uint4* gh = (const uint4*)(WhiG + (size_t)c0 * DIM);
            const uint4* gl = (const uint4*)(WloG + (size_t)c0 * DIM);
            char* bh = (char*)sHi; char* bl = (char*)sLo;
#pragma unroll
            for (int i = 0; i < (CHUNK * DIM / 8) / THREADS; ++i) {  // 2
                int idx = tid + THREADS * i;                          // uint4 idx
                int c = idx >> 3, k8 = idx & 7;
                int off = (c * 128 + k8 * 16) ^ ((c & 7) << 4);
                *(uint4*)(bh + off) = gh[idx];
                *(uint4*)(bl + off) = gl[idx];
            }
        }
        __syncthreads();

#pragma unroll
        for (int ct = 0; ct < CHUNK / 16; ++ct) {
            const int cloc = ct * 16 + r16;     // chunk-local code row of A frag
            const char* bh = (const char*)sHi;
            const char* bl = (const char*)sLo;
            const int sw = (cloc & 7) << 4;
            int o0 = (cloc * 128 + 16 * q) ^ sw;          // k-half 0
            int o1 = (cloc * 128 + 64 + 16 * q) ^ sw;     // k-half 1
            bf16x8 ah0 = *(const bf16x8*)(bh + o0);
            bf16x8 ah1 = *(const bf16x8*)(bh + o1);
            bf16x8 al0 = *(const bf16x8*)(bl + o0);
            bf16x8 al1 = *(const bf16x8*)(bl + o1);

            // C-init = B_j for this lane's 4 codes -> acc ends as t = B - 2*dot
            f32x4 acc = *(const f32x4*)&sB[c0 + ct * 16 + q * 4];

            acc = __builtin_amdgcn_mfma_f32_16x16x32_bf16(ah0, xh[0], acc, 0, 0, 0);
            acc = __builtin_amdgcn_mfma_f32_16x16x32_bf16(ah1, xh[1], acc, 0, 0, 0);
            acc = __builtin_amdgcn_mfma_f32_16x16x32_bf16(ah0, xl[0], acc, 0, 0, 0);
            acc = __builtin_amdgcn_mfma_f32_16x16x32_bf16(ah1, xl[1], acc, 0, 0, 0);
            acc = __builtin_amdgcn_mfma_f32_16x16x32_bf16(al0, xh[0], acc, 0, 0, 0);
            acc = __builtin_amdgcn_mfma_f32_16x16x32_bf16(al1, xh[1], acc, 0, 0, 0);

            const unsigned jbase = (unsigned)(c0 + ct * 16 + q * 4);
#pragma unroll
            for (int r = 0; r < 4; ++r) {
                unsigned key = t2key(acc[r], jbase + (unsigned)r);
                unsigned mx = min1 > key ? min1 : key;
                min2 = min2 < mx ? min2 : mx;
                min1 = min1 < key ? min1 : key;
            }
        }
    }

    // ---- merge the 4 lane-subsets of each row (lanes l, l^16, l^32, l^48) ----
    // Also merges the 4 partial ||x||^2 sums into the full per-row A.
#pragma unroll
    for (int d = 16; d <= 32; d <<= 1) {
        unsigned o1 = (unsigned)__shfl_xor((int)min1, d, 64);
        unsigned o2 = (unsigned)__shfl_xor((int)min2, d, 64);
        asum += __shfl_xor(asum, d, 64);
        unsigned n1 = min1 < o1 ? min1 : o1;
        unsigned mx = min1 > o1 ? min1 : o1;
        unsigned mn = min2 < o2 ? min2 : o2;
        unsigned n2 = mx < mn ? mx : mn;
        min1 = n1; min2 = n2;
    }

    const unsigned best = min1 & 511u;
    const float t1 = key2t(min1), t2 = key2t(min1 == min2 ? 0xFFFFFFFFu : min2);
    const bool flagged = (t2 < t1 + MARGIN_T);

    float ssev = 0.f;
    if (q == 0) {   // row owner: lanes 0..15 -> 16 consecutive rows, coalesced
        const int row = R0 + w * 16 + r16;
        // flag rows whose runner-up is within margin: fixup re-resolves exactly
        out[OFF_IDX + row] = (float)best + (flagged ? 1024.0f : 0.0f);
        if (!flagged) {
            ssev = asum + t1;                 // SSE = ||x||^2 + (B - 2*dot)
            atomicAdd(&sHist[best], 1u);
        }
    }
    // per-wave SSE reduce (owners hold nonzero), then block-level flush
#pragma unroll
    for (int off = 32; off; off >>= 1) ssev += __shfl_down(ssev, off);
    if (l == 0) sSseW[w] = (double)ssev;
    __syncthreads();

    {   // flush histogram to partial hist (spreads atomic contention 64x)
        unsigned c = sHist[tid];
        if (c) atomicAdd(&gHistP[(blockIdx.x & (NPART - 1)) * KCODES + tid], c);
    }
    if (tid == 0) {
        double s = 0.0;
#pragma unroll
        for (int i = 0; i < 8; ++i) s += sSseW[i];
        atomicAdd(sseAcc, s);                 // one fp64 atomic per block (2048 total)
    }
}

// ---------- fixup: exact numpy-fp32 argmin over ALL 512 codes, flagged rows ----------
// Also contributes the flagged rows' SSE (exact e) and histogram entries.

__global__ __launch_bounds__(256) void vq_fixup(
    const float* __restrict__ X, const float* __restrict__ W,
    const float* __restrict__ Bsc, float* __restrict__ out,
    double* __restrict__ sseAcc, unsigned* __restrict__ gHistP) {
    __shared__ float sx[DIM];
    __shared__ unsigned long long sKey[256];
    __shared__ float sFlagged[64];
    const int t = threadIdx.x;
    const int r0 = blockIdx.x * 64;
    double bsum = 0.0;
    int nfix = 0;

    if (t < 64) sFlagged[t] = out[OFF_IDX + r0 + t];
    __syncthreads();

    for (int i = 0; i < 64; ++i) {
        if (sFlagged[i] < 1024.0f) continue;    // uniform across block
        const int row = r0 + i;
        if (t < 64) sx[t] = X[(size_t)row * DIM + t];
        __syncthreads();
        const float A = np_sum_sq64(sx);        // numpy order, identical bits everywhere
        unsigned long long bk = ~0ULL;
        for (int c = t; c < KCODES; c += 256) {
            float e = np_e(W, c, sx, A, Bsc[c]);
            int iu = __float_as_int(e);
            unsigned u = ((unsigned)iu) ^ (((unsigned)(iu >> 31)) | 0x80000000u);
            unsigned long long key = ((unsigned long long)u << 32) | (unsigned)c;
            bk = bk < key ? bk : key;           // exact e, first-index tie-break
        }
        sKey[t] = bk;
        __syncthreads();
        for (int s = 128; s; s >>= 1) {
            if (t < s) { unsigned long long o = sKey[t + s]; if (o < sKey[t]) sKey[t] = o; }
            __syncthreads();
        }
        if (t == 0) {
            unsigned best = (unsigned)(sKey[0] & 511ULL);
            unsigned u = (unsigned)(sKey[0] >> 32);
            unsigned fb = (u & 0x80000000u) ? (u & 0x7FFFFFFFu) : ~u;
            float ebest = __uint_as_float(fb);  // exact np-fp32 e of the winner
            out[OFF_IDX + row] = (float)best;
            atomicAdd(&gHistP[(blockIdx.x & (NPART - 1)) * KCODES + best], 1u);
            bsum += (double)A + (double)ebest;  // SSE = A + e
            ++nfix;
        }
        __syncthreads();
    }
    if (t == 0 && nfix) atomicAdd(sseAcc, bsum);
}

// ---------- scatter: pure gather W[best] -> Q (no atomics, no X read) ----------
// One wave per row. Index load is wave-uniform, W gather is one coalesced
// 256B read (L2-hot), store coalesced. Runs on FINAL indices (post-fixup).

__global__ __launch_bounds__(256) void vq_scatter(
    const float* __restrict__ W, float* __restrict__ out) {
    const int gid = blockIdx.x * 256 + threadIdx.x;
    const int row = gid >> 6;
    const int lane = gid & 63;
    int idx = (int)out[OFF_IDX + row];
    if ((unsigned)idx >= KCODES) idx = KCODES - 1;   // safety clamp
    out[OFF_Q + (size_t)row * DIM + lane] = W[(size_t)idx * DIM + lane];
}

// ---------- finalize: sum partial hists -> perplexity; sse -> loss ----------

__global__ __launch_bounds__(512) void vq_finalize(
    const double* __restrict__ sseAcc, const unsigned* __restrict__ gHistP,
    float* __restrict__ out) {
    __shared__ float partial[8];
    const int t = threadIdx.x;
    unsigned c = 0;
#pragma unroll 8
    for (int p = 0; p < NPART; ++p) c += gHistP[p * KCODES + t];
    float pf = (float)c * (1.0f / (float)N_ROWS);
    float v = pf * logf(pf + 1e-10f);
#pragma unroll
    for (int off = 32; off; off >>= 1) v += __shfl_down(v, off);
    if ((t & 63) == 0) partial[t >> 6] = v;
    __syncthreads();
    if (t == 0) {
        float s = 0.f;
#pragma unroll
        for (int i = 0; i < 8; ++i) s += partial[i];
        out[OFF_PERP] = expf(-s) * (1.0f / (float)KCODES);
        out[0] = (float)(1.25 * sseAcc[0] * (1.0 / ((double)N_ROWS * (double)DIM)));
    }
}

extern "C" void kernel_launch(void* const* d_in, const int* in_sizes, int n_in,
                              void* d_out, int out_size, void* d_ws, size_t ws_size,
                              hipStream_t stream) {
    const float* X = (const float*)d_in[0];
    const float* W = (const float*)d_in[1];
    float* out = (float*)d_out;
    double* sseAcc = (double*)d_ws;

    size_t zb = 64;                                   // sseAcc
    if (zb > ws_size) zb = ws_size;
    hipMemsetAsync(d_ws, 0, zb, stream);

    // Scratch lives in the quantized region of `out` (dead until vq_scatter,
    // which runs LAST, overwrites it). Layout: WhiG | WloG | Bsc | gHistP.
    float* scratch = out + OFF_Q;
    unsigned short* WhiG = (unsigned short*)scratch;              // 64 KiB
    unsigned short* WloG = WhiG + (size_t)KCODES * DIM;           // 64 KiB
    float* Bsc = (float*)(WloG + (size_t)KCODES * DIM);           // 2 KiB
    unsigned* gHistP = (unsigned*)(Bsc + KCODES);                 // 128 KiB
    hipMemsetAsync(gHistP, 0, (size_t)NPART * KCODES * sizeof(unsigned), stream);

    vq_prep<<<2, 256, 0, stream>>>(W, WhiG, WloG, Bsc);
    vq_argmin<<<NBLOCKS, THREADS, 0, stream>>>(X, WhiG, WloG, Bsc, out, sseAcc, gHistP);
    vq_fixup<<<N_ROWS / 64, 256, 0, stream>>>(X, W, Bsc, out, sseAcc, gHistP);
    vq_finalize<<<1, 512, 0, stream>>>(sseAcc, gHistP, out);
    vq_scatter<<<(N_ROWS * DIM) / 256, 256, 0, stream>>>(W, out);
}